// Round 12
// baseline (79.462 us; speedup 1.0000x reference)
//
#include <hip/hip_runtime.h>
#include <hip/hip_bf16.h>

typedef __hip_bfloat16 bf16;
typedef __attribute__((ext_vector_type(8))) short bf16x8;   // 8 bf16 = 4 VGPR
typedef __attribute__((ext_vector_type(4))) float f32x4;

#define MFMA16(a, b, c) __builtin_amdgcn_mfma_f32_16x16x32_bf16((a), (b), (c), 0, 0, 0)

// ---- constants ----
// B=2, S=2048, D=768, HD=64, NH=12, NKV=4, GROUPS=3, WINDOW=384, theta=1e4, eps=1e-6
// I/O fp32; bf16 intermediates in ws; V stored transposed [b][kv][d][s].
// Ledger: best structure = dbuf + reg-prefetch + ONE barrier/iter (R11, 69.5us).
// R12: attention merges the 3 GQA q-heads of a kv-group into one block; K/V staged
// and fragment-read ONCE, reused in-register across heads. qkv/oproj unchanged.

__device__ __forceinline__ void st4bf(bf16* p, float4 v) {
    bf16 t[4];
    t[0] = __float2bfloat16(v.x); t[1] = __float2bfloat16(v.y);
    t[2] = __float2bfloat16(v.z); t[3] = __float2bfloat16(v.w);
    *reinterpret_cast<uint2*>(p) = *reinterpret_cast<const uint2*>(t);
}

// ============ Kernel 0: fp32->bf16 conversion of hs + weights, and RoPE table ======
__global__ __launch_bounds__(256) void k_prep(
    const float* __restrict__ hs, const float* __restrict__ qw,
    const float* __restrict__ kw, const float* __restrict__ vw,
    const float* __restrict__ ow,
    bf16* __restrict__ hsb, bf16* __restrict__ qwb, bf16* __restrict__ kwb,
    bf16* __restrict__ vwb, bf16* __restrict__ owb, float2* __restrict__ tab)
{
    const int bid = blockIdx.x, tid = threadIdx.x;
    const float* src; bf16* dst; int rel;
    if (bid < 3072)      { src = hs; dst = hsb; rel = bid; }
    else if (bid < 3648) { src = qw; dst = qwb; rel = bid - 3072; }
    else if (bid < 3840) { src = kw; dst = kwb; rel = bid - 3648; }
    else if (bid < 4032) { src = vw; dst = vwb; rel = bid - 3840; }
    else if (bid < 4608) { src = ow; dst = owb; rel = bid - 4032; }
    else {
        int i = (bid - 4608) * 256 + tid;          // 65536 entries
        int f = i & 31;
        float ang = (float)(i >> 5) * expf(-(float)f * 0.28782313662425572f);  // ln(1e4)/32
        float sn, cs; sincosf(ang, &sn, &cs);
        tab[i] = make_float2(cs, sn);
        return;
    }
    int i = (rel * 256 + tid) * 4;
    float4 v = *reinterpret_cast<const float4*>(src + i);
    st4bf(dst + i, v);
}

// ================= Kernel 1: MFMA QKV GEMM + RMSNorm + RoPE (R11, unchanged) =====
__global__ __launch_bounds__(256) void k_qkv(
    const bf16* __restrict__ hsb, const bf16* __restrict__ qwb,
    const bf16* __restrict__ kwb, const bf16* __restrict__ vwb,
    const float* __restrict__ qln, const float* __restrict__ kln,
    const float2* __restrict__ tab,
    bf16* __restrict__ qo, bf16* __restrict__ ko, bf16* __restrict__ vto)
{
    __shared__ bf16 As[2][64 * 72];
    __shared__ bf16 Bs[2][64 * 72];
    const int tid = threadIdx.x;
    const int w = tid >> 6, l = tid & 63;
    const int lm = l & 15, lg = l >> 4;
    const int m0 = blockIdx.x * 64;
    const int nblk = blockIdx.y;

    const bf16* wsrc; int wrow0, kind, head;
    if (nblk < 12)      { wsrc = qwb; wrow0 = nblk * 64;        kind = 0; head = nblk; }
    else if (nblk < 16) { wsrc = kwb; wrow0 = (nblk - 12) * 64; kind = 1; head = nblk - 12; }
    else                { wsrc = vwb; wrow0 = (nblk - 16) * 64; kind = 2; head = nblk - 16; }

    const int sr = tid >> 2, sc = (tid & 3) * 16;
    const bf16* aptr = hsb  + (size_t)(m0 + sr) * 768 + sc;
    const bf16* bptr = wsrc + (size_t)(wrow0 + sr) * 768 + sc;

    bf16x8 ra0 = *(const bf16x8*)(aptr);
    bf16x8 ra1 = *(const bf16x8*)(aptr + 8);
    bf16x8 rb0 = *(const bf16x8*)(bptr);
    bf16x8 rb1 = *(const bf16x8*)(bptr + 8);

    f32x4 acc[4] = {};
    for (int t = 0; t < 12; ++t) {
        const int p = t & 1;
        *(bf16x8*)(&As[p][sr * 72 + sc])     = ra0;
        *(bf16x8*)(&As[p][sr * 72 + sc + 8]) = ra1;
        *(bf16x8*)(&Bs[p][sr * 72 + sc])     = rb0;
        *(bf16x8*)(&Bs[p][sr * 72 + sc + 8]) = rb1;
        __syncthreads();
        if (t < 11) {
            const int off = (t + 1) * 64;
            ra0 = *(const bf16x8*)(aptr + off);
            ra1 = *(const bf16x8*)(aptr + off + 8);
            rb0 = *(const bf16x8*)(bptr + off);
            rb1 = *(const bf16x8*)(bptr + off + 8);
        }
        #pragma unroll
        for (int kk = 0; kk < 2; ++kk) {
            bf16x8 af = *(const bf16x8*)(&As[p][(w * 16 + lm) * 72 + kk * 32 + lg * 8]);
            #pragma unroll
            for (int ct = 0; ct < 4; ++ct) {
                bf16x8 bfr = *(const bf16x8*)(&Bs[p][(ct * 16 + lm) * 72 + kk * 32 + lg * 8]);
                acc[ct] = MFMA16(af, bfr, acc[ct]);
            }
        }
    }

    const int b  = m0 >> 11;
    const int s0 = m0 & 2047;

    if (kind == 2) {  // V: write TRANSPOSED [b][kv][d][s]
        bf16* base = vto + (size_t)(b * 4 + head) * 64 * 2048;
        #pragma unroll
        for (int r = 0; r < 4; ++r) {
            const int s = s0 + w * 16 + lg * 4 + r;
            #pragma unroll
            for (int ct = 0; ct < 4; ++ct)
                base[(size_t)(ct * 16 + lm) * 2048 + s] = __float2bfloat16(acc[ct][r]);
        }
        return;
    }

    const float* ln = (kind == 0) ? qln : kln;
    float lw[4];
    #pragma unroll
    for (int ct = 0; ct < 4; ++ct) lw[ct] = ln[ct * 16 + lm];

    bf16* base = (kind == 0) ? qo + ((size_t)(b * 12 + head) * 2048 + s0) * 64
                             : ko + ((size_t)(b * 4  + head) * 2048 + s0) * 64;
    #pragma unroll
    for (int r = 0; r < 4; ++r) {
        float n0 = acc[0][r], n1 = acc[1][r], n2 = acc[2][r], n3 = acc[3][r];
        float ss = n0 * n0 + n1 * n1 + n2 * n2 + n3 * n3;
        ss += __shfl_xor(ss, 1);
        ss += __shfl_xor(ss, 2);
        ss += __shfl_xor(ss, 4);
        ss += __shfl_xor(ss, 8);
        float rms = rsqrtf(ss * (1.0f / 64.0f) + 1e-6f);
        n0 *= rms * lw[0]; n1 *= rms * lw[1]; n2 *= rms * lw[2]; n3 *= rms * lw[3];
        const int row = w * 16 + lg * 4 + r;
        const float2* tp = tab + (size_t)(s0 + row) * 32;
        float2 t0 = tp[lm], t1 = tp[lm + 16];
        bf16* dst = base + (size_t)row * 64;
        dst[lm]      = __float2bfloat16(n0 * t0.x - n2 * t0.y);
        dst[lm + 16] = __float2bfloat16(n1 * t1.x - n3 * t1.y);
        dst[lm + 32] = __float2bfloat16(n2 * t0.x + n0 * t0.y);
        dst[lm + 48] = __float2bfloat16(n3 * t1.x + n1 * t1.y);
    }
}

// ================= Kernel 2: GQA-merged MFMA sliding-window attention ============
// grid (32 q-tiles, 4 kv-heads, 2 batch); block covers the kv-group's 3 q-heads.
// K/V staged once per tile; kf/vf fragments reused in-register across heads.
__global__ __launch_bounds__(256) void k_attn(
    const bf16* __restrict__ qi, const bf16* __restrict__ ki,
    const bf16* __restrict__ vti, bf16* __restrict__ ao)
{
    __shared__ bf16 Ks[2][64 * 72];   // [key][d]
    __shared__ bf16 Vs[2][64 * 72];   // [d][key]
    __shared__ bf16 Ps[64 * 72];      // per-wave-private rows, reused per head
    const int tid = threadIdx.x;
    const int w = tid >> 6, l = tid & 63;
    const int lm = l & 15, lg = l >> 4;
    const int qb = blockIdx.x, kvh = blockIdx.y, b = blockIdx.z;
    const int q0 = qb * 64;
    const float SCL2 = 0.18033688011117042f;   // 0.125 * log2(e)

    bf16x8 qf0[3], qf1[3];
    #pragma unroll
    for (int hh = 0; hh < 3; ++hh) {
        const bf16* qbase = qi + ((size_t)((b * 12 + kvh * 3 + hh) * 2048 + q0 + w * 16 + lm)) * 64 + lg * 8;
        qf0[hh] = *(const bf16x8*)(qbase);
        qf1[hh] = *(const bf16x8*)(qbase + 32);
    }

    f32x4 oacc[3][4] = {};
    float m_[3][4], l_[3][4];
    #pragma unroll
    for (int hh = 0; hh < 3; ++hh)
        #pragma unroll
        for (int r = 0; r < 4; ++r) { m_[hh][r] = -INFINITY; l_[hh][r] = 0.f; }

    const int sr = tid >> 2, sc = (tid & 3) * 16;
    const bf16* kgb = ki  + (size_t)(b * 4 + kvh) * 2048 * 64;
    const bf16* vgb = vti + (size_t)(b * 4 + kvh) * 64 * 2048;

    const int kb_lo = (qb > 6) ? (qb - 6) : 0;
    bf16x8 rk0, rk1, rv0, rv1;
    {
        const bf16* kp = kgb + (size_t)(kb_lo * 64 + sr) * 64 + sc;
        const bf16* vp = vgb + (size_t)sr * 2048 + kb_lo * 64 + sc;
        rk0 = *(const bf16x8*)(kp);
        rk1 = *(const bf16x8*)(kp + 8);
        rv0 = *(const bf16x8*)(vp);
        rv1 = *(const bf16x8*)(vp + 8);
    }

    for (int kb = kb_lo; kb <= qb; ++kb) {
        const int p = (kb - kb_lo) & 1;
        const int k0 = kb * 64;

        *(bf16x8*)(&Ks[p][sr * 72 + sc])     = rk0;
        *(bf16x8*)(&Ks[p][sr * 72 + sc + 8]) = rk1;
        *(bf16x8*)(&Vs[p][sr * 72 + sc])     = rv0;
        *(bf16x8*)(&Vs[p][sr * 72 + sc + 8]) = rv1;
        __syncthreads();
        if (kb < qb) {
            const bf16* kp = kgb + (size_t)(k0 + 64 + sr) * 64 + sc;
            const bf16* vp = vgb + (size_t)sr * 2048 + k0 + 64 + sc;
            rk0 = *(const bf16x8*)(kp);
            rk1 = *(const bf16x8*)(kp + 8);
            rv0 = *(const bf16x8*)(vp);
            rv1 = *(const bf16x8*)(vp + 8);
        }

        // QK^T: K fragments loaded once, used by all 3 heads
        f32x4 sacc[3][4];
        #pragma unroll
        for (int kt = 0; kt < 4; ++kt) {
            bf16x8 kf0 = *(const bf16x8*)(&Ks[p][(kt * 16 + lm) * 72 + lg * 8]);
            bf16x8 kf1 = *(const bf16x8*)(&Ks[p][(kt * 16 + lm) * 72 + 32 + lg * 8]);
            #pragma unroll
            for (int hh = 0; hh < 3; ++hh) {
                f32x4 z = {0.f, 0.f, 0.f, 0.f};
                z = MFMA16(qf0[hh], kf0, z);
                sacc[hh][kt] = MFMA16(qf1[hh], kf1, z);
            }
        }

        const bool need_mask = (kb == qb) || (kb == qb - 6);   // wave-uniform
        bf16x8 pf0[3], pf1[3];
        #pragma unroll
        for (int hh = 0; hh < 3; ++hh) {
            float pmax[4] = {-INFINITY, -INFINITY, -INFINITY, -INFINITY};
            if (need_mask) {
                #pragma unroll
                for (int kt = 0; kt < 4; ++kt)
                    #pragma unroll
                    for (int r = 0; r < 4; ++r) {
                        int kgl = k0 + kt * 16 + lm;
                        int qgl = q0 + w * 16 + lg * 4 + r;
                        bool ok = (kgl <= qgl) && (kgl > qgl - 384);
                        float s = ok ? sacc[hh][kt][r] * SCL2 : -INFINITY;
                        sacc[hh][kt][r] = s;
                        pmax[r] = fmaxf(pmax[r], s);
                    }
            } else {
                #pragma unroll
                for (int kt = 0; kt < 4; ++kt)
                    #pragma unroll
                    for (int r = 0; r < 4; ++r) {
                        float s = sacc[hh][kt][r] * SCL2;
                        sacc[hh][kt][r] = s;
                        pmax[r] = fmaxf(pmax[r], s);
                    }
            }
            #pragma unroll
            for (int r = 0; r < 4; ++r) {
                float t = pmax[r];
                t = fmaxf(t, __shfl_xor(t, 1));
                t = fmaxf(t, __shfl_xor(t, 2));
                t = fmaxf(t, __shfl_xor(t, 4));
                t = fmaxf(t, __shfl_xor(t, 8));
                pmax[r] = t;
            }

            if (need_mask) {
                #pragma unroll
                for (int r = 0; r < 4; ++r) {
                    float mnew = fmaxf(m_[hh][r], pmax[r]);
                    float scale, rs = 0.f, pv[4];
                    if (mnew > -INFINITY) {   // window-edge tile has a fully-masked row
                        scale = exp2f(m_[hh][r] - mnew);
                        #pragma unroll
                        for (int kt = 0; kt < 4; ++kt) { pv[kt] = exp2f(sacc[hh][kt][r] - mnew); rs += pv[kt]; }
                    } else {
                        scale = 1.f;
                        #pragma unroll
                        for (int kt = 0; kt < 4; ++kt) pv[kt] = 0.f;
                    }
                    m_[hh][r] = mnew;
                    rs += __shfl_xor(rs, 1);
                    rs += __shfl_xor(rs, 2);
                    rs += __shfl_xor(rs, 4);
                    rs += __shfl_xor(rs, 8);
                    l_[hh][r] = l_[hh][r] * scale + rs;
                    #pragma unroll
                    for (int dt = 0; dt < 4; ++dt) oacc[hh][dt][r] *= scale;
                    #pragma unroll
                    for (int kt = 0; kt < 4; ++kt)
                        Ps[(w * 16 + lg * 4 + r) * 72 + kt * 16 + lm] = __float2bfloat16(pv[kt]);
                }
            } else {
                #pragma unroll
                for (int r = 0; r < 4; ++r) {
                    float mnew = fmaxf(m_[hh][r], pmax[r]);   // pmax finite here
                    float scale = exp2f(m_[hh][r] - mnew);
                    float rs = 0.f, pv[4];
                    #pragma unroll
                    for (int kt = 0; kt < 4; ++kt) { pv[kt] = exp2f(sacc[hh][kt][r] - mnew); rs += pv[kt]; }
                    m_[hh][r] = mnew;
                    rs += __shfl_xor(rs, 1);
                    rs += __shfl_xor(rs, 2);
                    rs += __shfl_xor(rs, 4);
                    rs += __shfl_xor(rs, 8);
                    l_[hh][r] = l_[hh][r] * scale + rs;
                    #pragma unroll
                    for (int dt = 0; dt < 4; ++dt) oacc[hh][dt][r] *= scale;
                    #pragma unroll
                    for (int kt = 0; kt < 4; ++kt)
                        Ps[(w * 16 + lg * 4 + r) * 72 + kt * 16 + lm] = __float2bfloat16(pv[kt]);
                }
            }
            // read this head's P fragments before next head overwrites Ps
            // (wave-private rows; same-wave DS ops execute in order)
            pf0[hh] = *(const bf16x8*)(&Ps[(w * 16 + lm) * 72 + lg * 8]);
            pf1[hh] = *(const bf16x8*)(&Ps[(w * 16 + lm) * 72 + 32 + lg * 8]);
        }

        // PV: V fragments loaded once, used by all 3 heads
        #pragma unroll
        for (int dt = 0; dt < 4; ++dt) {
            bf16x8 vf0 = *(const bf16x8*)(&Vs[p][(dt * 16 + lm) * 72 + lg * 8]);
            bf16x8 vf1 = *(const bf16x8*)(&Vs[p][(dt * 16 + lm) * 72 + 32 + lg * 8]);
            #pragma unroll
            for (int hh = 0; hh < 3; ++hh) {
                oacc[hh][dt] = MFMA16(pf0[hh], vf0, oacc[hh][dt]);
                oacc[hh][dt] = MFMA16(pf1[hh], vf1, oacc[hh][dt]);
            }
        }
    }

    #pragma unroll
    for (int hh = 0; hh < 3; ++hh)
        #pragma unroll
        for (int r = 0; r < 4; ++r) {
            float inv = 1.f / l_[hh][r];
            bf16* dst = ao + ((size_t)(b * 2048 + q0 + w * 16 + lg * 4 + r)) * 768 + (kvh * 3 + hh) * 64;
            #pragma unroll
            for (int dt = 0; dt < 4; ++dt)
                dst[dt * 16 + lm] = __float2bfloat16(oacc[hh][dt][r] * inv);
        }
}

// ================= Kernel 3: MFMA output projection (R11, unchanged) =============
__global__ __launch_bounds__(256) void k_oproj(
    const bf16* __restrict__ A, const bf16* __restrict__ W, float* __restrict__ out)
{
    __shared__ bf16 As[2][64 * 72];
    __shared__ bf16 Bs[2][64 * 72];
    const int tid = threadIdx.x;
    const int w = tid >> 6, l = tid & 63;
    const int lm = l & 15, lg = l >> 4;
    const int m0 = blockIdx.x * 64, n0 = blockIdx.y * 64;

    const int sr = tid >> 2, sc = (tid & 3) * 16;
    const bf16* aptr = A + (size_t)(m0 + sr) * 768 + sc;
    const bf16* bptr = W + (size_t)(n0 + sr) * 768 + sc;

    bf16x8 ra0 = *(const bf16x8*)(aptr);
    bf16x8 ra1 = *(const bf16x8*)(aptr + 8);
    bf16x8 rb0 = *(const bf16x8*)(bptr);
    bf16x8 rb1 = *(const bf16x8*)(bptr + 8);

    f32x4 acc[4] = {};
    for (int t = 0; t < 12; ++t) {
        const int p = t & 1;
        *(bf16x8*)(&As[p][sr * 72 + sc])     = ra0;
        *(bf16x8*)(&As[p][sr * 72 + sc + 8]) = ra1;
        *(bf16x8*)(&Bs[p][sr * 72 + sc])     = rb0;
        *(bf16x8*)(&Bs[p][sr * 72 + sc + 8]) = rb1;
        __syncthreads();
        if (t < 11) {
            const int off = (t + 1) * 64;
            ra0 = *(const bf16x8*)(aptr + off);
            ra1 = *(const bf16x8*)(aptr + off + 8);
            rb0 = *(const bf16x8*)(bptr + off);
            rb1 = *(const bf16x8*)(bptr + off + 8);
        }
        #pragma unroll
        for (int kk = 0; kk < 2; ++kk) {
            bf16x8 af = *(const bf16x8*)(&As[p][(w * 16 + lm) * 72 + kk * 32 + lg * 8]);
            #pragma unroll
            for (int ct = 0; ct < 4; ++ct) {
                bf16x8 bfr = *(const bf16x8*)(&Bs[p][(ct * 16 + lm) * 72 + kk * 32 + lg * 8]);
                acc[ct] = MFMA16(af, bfr, acc[ct]);
            }
        }
    }

    #pragma unroll
    for (int r = 0; r < 4; ++r) {
        float* dst = out + (size_t)(m0 + w * 16 + lg * 4 + r) * 768 + n0;
        #pragma unroll
        for (int ct = 0; ct < 4; ++ct)
            dst[ct * 16 + lm] = acc[ct][r];
    }
}

extern "C" void kernel_launch(void* const* d_in, const int* in_sizes, int n_in,
                              void* d_out, int out_size, void* d_ws, size_t ws_size,
                              hipStream_t stream) {
    const float* hs  = (const float*)d_in[0];
    const float* qw  = (const float*)d_in[1];
    const float* kw  = (const float*)d_in[2];
    const float* vw  = (const float*)d_in[3];
    const float* ow  = (const float*)d_in[4];
    const float* qln = (const float*)d_in[5];
    const float* kln = (const float*)d_in[6];
    float* out = (float*)d_out;

    float2* tab  = (float2*)d_ws;
    bf16*   q_ws = (bf16*)(tab + 65536);
    bf16*   k_ws = q_ws + 3145728;
    bf16*   vt_ws= k_ws + 1048576;
    bf16*   x_ws = vt_ws + 1048576;    // hsb during k_qkv, attn output after
    bf16*   qwb  = x_ws + 3145728;
    bf16*   kwb  = qwb + 589824;
    bf16*   vwb  = kwb + 196608;
    bf16*   owb  = vwb + 196608;

    k_prep<<<dim3(4864), 256, 0, stream>>>(hs, qw, kw, vw, ow, x_ws, qwb, kwb, vwb, owb, tab);
    k_qkv<<<dim3(64, 20, 1), 256, 0, stream>>>(x_ws, qwb, kwb, vwb, qln, kln, tab, q_ws, k_ws, vt_ws);
    k_attn<<<dim3(32, 4, 2), 256, 0, stream>>>(q_ws, k_ws, vt_ws, x_ws);
    k_oproj<<<dim3(64, 12, 1), 256, 0, stream>>>(x_ws, owb, out);
}

// Round 13
// 68.222 us; speedup vs baseline: 1.1647x; 1.1647x over previous
//
#include <hip/hip_runtime.h>
#include <hip/hip_bf16.h>

typedef __hip_bfloat16 bf16;
typedef __attribute__((ext_vector_type(8))) short bf16x8;    // 8 bf16 = 4 VGPR
typedef __attribute__((ext_vector_type(4))) float f32x4;
typedef __attribute__((ext_vector_type(16))) float f32x16;

#define MFMA16(a, b, c) __builtin_amdgcn_mfma_f32_16x16x32_bf16((a), (b), (c), 0, 0, 0)
#define MFMA32(a, b, c) __builtin_amdgcn_mfma_f32_32x32x16_bf16((a), (b), (c), 0, 0, 0)

// ---- constants ----
// B=2, S=2048, D=768, HD=64, NH=12, NKV=4, GROUPS=3, WINDOW=384, theta=1e4, eps=1e-6
// I/O fp32; bf16 ws intermediates; V^T [b][kv][d][s]; Q pre-scaled by 0.125*log2(e).
// Ledger: R11=69.5 best. R12 GQA-merge: 1 blk/CU disaster (58us attn) but measured
// rest-of-pipeline ~20us -> attn ~48us dominates. R13: swapped-QK 32x32 in-reg softmax.

__device__ __forceinline__ void st4bf(bf16* p, float4 v) {
    bf16 t[4];
    t[0] = __float2bfloat16(v.x); t[1] = __float2bfloat16(v.y);
    t[2] = __float2bfloat16(v.z); t[3] = __float2bfloat16(v.w);
    *reinterpret_cast<uint2*>(p) = *reinterpret_cast<const uint2*>(t);
}

// ============ Kernel 0: fp32->bf16 conversion + RoPE table ============
__global__ __launch_bounds__(256) void k_prep(
    const float* __restrict__ hs, const float* __restrict__ qw,
    const float* __restrict__ kw, const float* __restrict__ vw,
    const float* __restrict__ ow,
    bf16* __restrict__ hsb, bf16* __restrict__ qwb, bf16* __restrict__ kwb,
    bf16* __restrict__ vwb, bf16* __restrict__ owb, float2* __restrict__ tab)
{
    const int bid = blockIdx.x, tid = threadIdx.x;
    const float* src; bf16* dst; int rel;
    if (bid < 3072)      { src = hs; dst = hsb; rel = bid; }
    else if (bid < 3648) { src = qw; dst = qwb; rel = bid - 3072; }
    else if (bid < 3840) { src = kw; dst = kwb; rel = bid - 3648; }
    else if (bid < 4032) { src = vw; dst = vwb; rel = bid - 3840; }
    else if (bid < 4608) { src = ow; dst = owb; rel = bid - 4032; }
    else {
        int i = (bid - 4608) * 256 + tid;
        int f = i & 31;
        float ang = (float)(i >> 5) * expf(-(float)f * 0.28782313662425572f);
        float sn, cs; sincosf(ang, &sn, &cs);
        tab[i] = make_float2(cs, sn);
        return;
    }
    int i = (rel * 256 + tid) * 4;
    float4 v = *reinterpret_cast<const float4*>(src + i);
    st4bf(dst + i, v);
}

// ================= Kernel 1: MFMA QKV GEMM + RMSNorm + RoPE (R11) =================
// Q output is pre-scaled by 0.125*log2(e) so attention scores are log2-space direct.
__global__ __launch_bounds__(256) void k_qkv(
    const bf16* __restrict__ hsb, const bf16* __restrict__ qwb,
    const bf16* __restrict__ kwb, const bf16* __restrict__ vwb,
    const float* __restrict__ qln, const float* __restrict__ kln,
    const float2* __restrict__ tab,
    bf16* __restrict__ qo, bf16* __restrict__ ko, bf16* __restrict__ vto)
{
    __shared__ bf16 As[2][64 * 72];
    __shared__ bf16 Bs[2][64 * 72];
    const int tid = threadIdx.x;
    const int w = tid >> 6, l = tid & 63;
    const int lm = l & 15, lg = l >> 4;
    const int m0 = blockIdx.x * 64;
    const int nblk = blockIdx.y;

    const bf16* wsrc; int wrow0, kind, head;
    if (nblk < 12)      { wsrc = qwb; wrow0 = nblk * 64;        kind = 0; head = nblk; }
    else if (nblk < 16) { wsrc = kwb; wrow0 = (nblk - 12) * 64; kind = 1; head = nblk - 12; }
    else                { wsrc = vwb; wrow0 = (nblk - 16) * 64; kind = 2; head = nblk - 16; }

    const int sr = tid >> 2, sc = (tid & 3) * 16;
    const bf16* aptr = hsb  + (size_t)(m0 + sr) * 768 + sc;
    const bf16* bptr = wsrc + (size_t)(wrow0 + sr) * 768 + sc;

    bf16x8 ra0 = *(const bf16x8*)(aptr);
    bf16x8 ra1 = *(const bf16x8*)(aptr + 8);
    bf16x8 rb0 = *(const bf16x8*)(bptr);
    bf16x8 rb1 = *(const bf16x8*)(bptr + 8);

    f32x4 acc[4] = {};
    for (int t = 0; t < 12; ++t) {
        const int p = t & 1;
        *(bf16x8*)(&As[p][sr * 72 + sc])     = ra0;
        *(bf16x8*)(&As[p][sr * 72 + sc + 8]) = ra1;
        *(bf16x8*)(&Bs[p][sr * 72 + sc])     = rb0;
        *(bf16x8*)(&Bs[p][sr * 72 + sc + 8]) = rb1;
        __syncthreads();
        if (t < 11) {
            const int off = (t + 1) * 64;
            ra0 = *(const bf16x8*)(aptr + off);
            ra1 = *(const bf16x8*)(aptr + off + 8);
            rb0 = *(const bf16x8*)(bptr + off);
            rb1 = *(const bf16x8*)(bptr + off + 8);
        }
        #pragma unroll
        for (int kk = 0; kk < 2; ++kk) {
            bf16x8 af = *(const bf16x8*)(&As[p][(w * 16 + lm) * 72 + kk * 32 + lg * 8]);
            #pragma unroll
            for (int ct = 0; ct < 4; ++ct) {
                bf16x8 bfr = *(const bf16x8*)(&Bs[p][(ct * 16 + lm) * 72 + kk * 32 + lg * 8]);
                acc[ct] = MFMA16(af, bfr, acc[ct]);
            }
        }
    }

    const int b  = m0 >> 11;
    const int s0 = m0 & 2047;

    if (kind == 2) {
        bf16* base = vto + (size_t)(b * 4 + head) * 64 * 2048;
        #pragma unroll
        for (int r = 0; r < 4; ++r) {
            const int s = s0 + w * 16 + lg * 4 + r;
            #pragma unroll
            for (int ct = 0; ct < 4; ++ct)
                base[(size_t)(ct * 16 + lm) * 2048 + s] = __float2bfloat16(acc[ct][r]);
        }
        return;
    }

    const float* ln = (kind == 0) ? qln : kln;
    const float qscl = (kind == 0) ? 0.18033688011117042f : 1.0f;  // 0.125*log2(e) folded into Q
    float lw[4];
    #pragma unroll
    for (int ct = 0; ct < 4; ++ct) lw[ct] = ln[ct * 16 + lm] * qscl;

    bf16* base = (kind == 0) ? qo + ((size_t)(b * 12 + head) * 2048 + s0) * 64
                             : ko + ((size_t)(b * 4  + head) * 2048 + s0) * 64;
    #pragma unroll
    for (int r = 0; r < 4; ++r) {
        float n0 = acc[0][r], n1 = acc[1][r], n2 = acc[2][r], n3 = acc[3][r];
        float ss = n0 * n0 + n1 * n1 + n2 * n2 + n3 * n3;
        ss += __shfl_xor(ss, 1);
        ss += __shfl_xor(ss, 2);
        ss += __shfl_xor(ss, 4);
        ss += __shfl_xor(ss, 8);
        float rms = rsqrtf(ss * (1.0f / 64.0f) + 1e-6f);
        n0 *= rms * lw[0]; n1 *= rms * lw[1]; n2 *= rms * lw[2]; n3 *= rms * lw[3];
        const int row = w * 16 + lg * 4 + r;
        const float2* tp = tab + (size_t)(s0 + row) * 32;
        float2 t0 = tp[lm], t1 = tp[lm + 16];
        bf16* dst = base + (size_t)row * 64;
        dst[lm]      = __float2bfloat16(n0 * t0.x - n2 * t0.y);
        dst[lm + 16] = __float2bfloat16(n1 * t1.x - n3 * t1.y);
        dst[lm + 32] = __float2bfloat16(n2 * t0.x + n0 * t0.y);
        dst[lm + 48] = __float2bfloat16(n3 * t1.x + n1 * t1.y);
    }
}

// ================= Kernel 2: swapped-QK 32x32 attention, in-register softmax =====
// grid (32 q-tiles of 64, 12 heads, 2 batch), 128 threads = 2 waves; wave w owns
// q in [q0+32w, q0+32w+32). mfma32(K,Q) -> S^T: lane owns q = lane&31; softmax is
// in-lane + one shfl_xor(32). O accumulated as O^T = V^T * P^T (q stays lane-local).
__global__ __launch_bounds__(128) void k_attn(
    const bf16* __restrict__ qi, const bf16* __restrict__ ki,
    const bf16* __restrict__ vti, bf16* __restrict__ ao)
{
    __shared__ bf16 Ks[2][64 * 72];   // [k_local][d]
    __shared__ bf16 Vs[2][64 * 72];   // [d][k_local]
    const int tid = threadIdx.x;
    const int w = tid >> 6, l = tid & 63;
    const int p = l >> 5, c31 = l & 31;
    const int qb = blockIdx.x, h = blockIdx.y, b = blockIdx.z;
    const int kv = h / 3;
    const int q0 = qb * 64;
    const int qw0 = q0 + w * 32;
    const int q_g = qw0 + c31;        // this lane's q row (lane-local through everything)

    // Q fragments (B-operand): lane holds Q[q=c31][d = c*16 + p*8 + j]
    const bf16* qrow = qi + ((size_t)((b * 12 + h) * 2048 + q_g)) * 64 + p * 8;
    bf16x8 qf0 = *(const bf16x8*)(qrow);
    bf16x8 qf1 = *(const bf16x8*)(qrow + 16);
    bf16x8 qf2 = *(const bf16x8*)(qrow + 32);
    bf16x8 qf3 = *(const bf16x8*)(qrow + 48);

    f32x16 oacc0 = {}, oacc1 = {};    // O^T[d = dt*32 + rowfmla][q = c31]
    float m_ = -INFINITY, l_ = 0.f;

    const int sr = tid >> 1, sc = (tid & 1) * 32;   // staging: row, 32-col half
    const bf16* kgb = ki  + (size_t)(b * 4 + kv) * 2048 * 64;
    const bf16* vgb = vti + (size_t)(b * 4 + kv) * 64 * 2048;

    const int kb_lo = (qb > 6) ? (qb - 6) : 0;
    bf16x8 rk[4], rv[4];
    {
        const bf16* kp = kgb + (size_t)(kb_lo * 64 + sr) * 64 + sc;
        const bf16* vp = vgb + (size_t)sr * 2048 + kb_lo * 64 + sc;
        #pragma unroll
        for (int j = 0; j < 4; ++j) {
            rk[j] = *(const bf16x8*)(kp + j * 8);
            rv[j] = *(const bf16x8*)(vp + j * 8);
        }
    }

    for (int kb = kb_lo; kb <= qb; ++kb) {
        const int pb = (kb - kb_lo) & 1;
        const int k0 = kb * 64;

        #pragma unroll
        for (int j = 0; j < 4; ++j) {
            *(bf16x8*)(&Ks[pb][sr * 72 + sc + j * 8]) = rk[j];
            *(bf16x8*)(&Vs[pb][sr * 72 + sc + j * 8]) = rv[j];
        }
        __syncthreads();
        if (kb < qb) {
            const bf16* kp = kgb + (size_t)(k0 + 64 + sr) * 64 + sc;
            const bf16* vp = vgb + (size_t)sr * 2048 + k0 + 64 + sc;
            #pragma unroll
            for (int j = 0; j < 4; ++j) {
                rk[j] = *(const bf16x8*)(kp + j * 8);
                rv[j] = *(const bf16x8*)(vp + j * 8);
            }
        }

        // S^T = K·Q^T (two 32-key tiles). A-frag: lane holds K[k=kt*32+c31][d-chunk].
        f32x16 s0 = {}, s1 = {};
        {
            const bf16* kbase = &Ks[pb][c31 * 72 + p * 8];
            s0 = MFMA32(*(const bf16x8*)(kbase),      qf0, s0);
            s0 = MFMA32(*(const bf16x8*)(kbase + 16), qf1, s0);
            s0 = MFMA32(*(const bf16x8*)(kbase + 32), qf2, s0);
            s0 = MFMA32(*(const bf16x8*)(kbase + 48), qf3, s0);
            const bf16* kbase1 = kbase + 32 * 72;
            s1 = MFMA32(*(const bf16x8*)(kbase1),      qf0, s1);
            s1 = MFMA32(*(const bf16x8*)(kbase1 + 16), qf1, s1);
            s1 = MFMA32(*(const bf16x8*)(kbase1 + 32), qf2, s1);
            s1 = MFMA32(*(const bf16x8*)(kbase1 + 48), qf3, s1);
        }

        // mask (wave-uniform branch). D row formula: k_local = (reg&3)+8*(reg>>2)+4p.
        const bool need_mask = (64 * kb + 63 > qw0) || (64 * kb <= qw0 - 353);
        if (need_mask) {
            #pragma unroll
            for (int r = 0; r < 16; ++r) {
                int kl = (r & 3) + 8 * (r >> 2) + 4 * p;
                int kg0 = k0 + kl, kg1 = k0 + 32 + kl;
                bool ok0 = (kg0 <= q_g) && (kg0 > q_g - 384);
                bool ok1 = (kg1 <= q_g) && (kg1 > q_g - 384);
                s0[r] = ok0 ? s0[r] : -INFINITY;
                s1[r] = ok1 ? s1[r] : -INFINITY;
            }
        }

        // row max: in-lane over 32 + one cross-half exchange
        float tmax = s0[0];
        #pragma unroll
        for (int r = 1; r < 16; ++r) tmax = fmaxf(tmax, s0[r]);
        #pragma unroll
        for (int r = 0; r < 16; ++r) tmax = fmaxf(tmax, s1[r]);
        tmax = fmaxf(tmax, __shfl_xor(tmax, 32));

        float mnew = fmaxf(m_, tmax);
        float scale, rs = 0.f;
        if (mnew > -INFINITY) {
            scale = exp2f(m_ - mnew);
            #pragma unroll
            for (int r = 0; r < 16; ++r) { s0[r] = exp2f(s0[r] - mnew); rs += s0[r]; }
            #pragma unroll
            for (int r = 0; r < 16; ++r) { s1[r] = exp2f(s1[r] - mnew); rs += s1[r]; }
        } else {                       // fully-masked so far (window leading edge row)
            scale = 1.f;
            #pragma unroll
            for (int r = 0; r < 16; ++r) { s0[r] = 0.f; s1[r] = 0.f; }
        }
        m_ = mnew;
        rs += __shfl_xor(rs, 32);
        l_ = l_ * scale + rs;
        #pragma unroll
        for (int r = 0; r < 16; ++r) { oacc0[r] *= scale; oacc1[r] *= scale; }

        // pack P into B-operand fragments paf[c] (c-th K16 chunk): lane needs
        // P[q=c31][k = c*16 + p*8 + j]. Own regs cover k≡{4p..4p+3} mod 8; partner
        // half arrives via shfl_xor(32). Derivation: pk[i]=(pv[2i],pv[2i+1]) covers
        // k = 8*(i>>1) + 4p + 2*(i&1) + {0,1}; frag u32s select own/partner halves.
        bf16x8 paf[4];
        #pragma unroll
        for (int kt = 0; kt < 2; ++kt) {
            unsigned pk[8];
            #pragma unroll
            for (int i = 0; i < 8; ++i) {
                float lo = (kt == 0) ? s0[2 * i] : s1[2 * i];
                float hi = (kt == 0) ? s0[2 * i + 1] : s1[2 * i + 1];
                bf16 blo = __float2bfloat16(lo), bhi = __float2bfloat16(hi);
                pk[i] = ((unsigned)*(unsigned short*)&bhi << 16) | (unsigned)*(unsigned short*)&blo;
            }
            unsigned x[8];
            #pragma unroll
            for (int i = 0; i < 8; ++i) x[i] = (unsigned)__shfl_xor((int)pk[i], 32);
            #pragma unroll
            for (int s = 0; s < 2; ++s) {
                union { int4 i4; bf16x8 v; } u;
                u.i4.x = p ? (int)x[4 * s + 2] : (int)pk[4 * s];
                u.i4.y = p ? (int)x[4 * s + 3] : (int)pk[4 * s + 1];
                u.i4.z = p ? (int)pk[4 * s + 2] : (int)x[4 * s];
                u.i4.w = p ? (int)pk[4 * s + 3] : (int)x[4 * s + 1];
                paf[kt * 2 + s] = u.v;
            }
        }

        // O^T += V^T · P^T. A-frag: lane holds V^T[d=dt*32+c31][k-chunk c].
        {
            const bf16* vbase = &Vs[pb][c31 * 72 + p * 8];
            oacc0 = MFMA32(*(const bf16x8*)(vbase),      paf[0], oacc0);
            oacc0 = MFMA32(*(const bf16x8*)(vbase + 16), paf[1], oacc0);
            oacc0 = MFMA32(*(const bf16x8*)(vbase + 32), paf[2], oacc0);
            oacc0 = MFMA32(*(const bf16x8*)(vbase + 48), paf[3], oacc0);
            const bf16* vbase1 = vbase + 32 * 72;
            oacc1 = MFMA32(*(const bf16x8*)(vbase1),      paf[0], oacc1);
            oacc1 = MFMA32(*(const bf16x8*)(vbase1 + 16), paf[1], oacc1);
            oacc1 = MFMA32(*(const bf16x8*)(vbase1 + 32), paf[2], oacc1);
            oacc1 = MFMA32(*(const bf16x8*)(vbase1 + 48), paf[3], oacc1);
        }
        __syncthreads();   // all waves done with Ks/Vs[pb] before next write
    }

    // epilogue: lane writes O[q_g][d] for d = dt*32 + 8g + 4p + {0..3}
    const float inv = 1.f / l_;
    bf16* dst = ao + ((size_t)(b * 2048 + q_g)) * 768 + h * 64;
    #pragma unroll
    for (int g = 0; g < 4; ++g) {
        union { uint2 u2; bf16 t[4]; } o0, o1;
        #pragma unroll
        for (int e = 0; e < 4; ++e) {
            o0.t[e] = __float2bfloat16(oacc0[4 * g + e] * inv);
            o1.t[e] = __float2bfloat16(oacc1[4 * g + e] * inv);
        }
        *reinterpret_cast<uint2*>(dst + 8 * g + 4 * p)      = o0.u2;
        *reinterpret_cast<uint2*>(dst + 32 + 8 * g + 4 * p) = o1.u2;
    }
}

// ================= Kernel 3: MFMA output projection (R11, unchanged) =============
__global__ __launch_bounds__(256) void k_oproj(
    const bf16* __restrict__ A, const bf16* __restrict__ W, float* __restrict__ out)
{
    __shared__ bf16 As[2][64 * 72];
    __shared__ bf16 Bs[2][64 * 72];
    const int tid = threadIdx.x;
    const int w = tid >> 6, l = tid & 63;
    const int lm = l & 15, lg = l >> 4;
    const int m0 = blockIdx.x * 64, n0 = blockIdx.y * 64;

    const int sr = tid >> 2, sc = (tid & 3) * 16;
    const bf16* aptr = A + (size_t)(m0 + sr) * 768 + sc;
    const bf16* bptr = W + (size_t)(n0 + sr) * 768 + sc;

    bf16x8 ra0 = *(const bf16x8*)(aptr);
    bf16x8 ra1 = *(const bf16x8*)(aptr + 8);
    bf16x8 rb0 = *(const bf16x8*)(bptr);
    bf16x8 rb1 = *(const bf16x8*)(bptr + 8);

    f32x4 acc[4] = {};
    for (int t = 0; t < 12; ++t) {
        const int p = t & 1;
        *(bf16x8*)(&As[p][sr * 72 + sc])     = ra0;
        *(bf16x8*)(&As[p][sr * 72 + sc + 8]) = ra1;
        *(bf16x8*)(&Bs[p][sr * 72 + sc])     = rb0;
        *(bf16x8*)(&Bs[p][sr * 72 + sc + 8]) = rb1;
        __syncthreads();
        if (t < 11) {
            const int off = (t + 1) * 64;
            ra0 = *(const bf16x8*)(aptr + off);
            ra1 = *(const bf16x8*)(aptr + off + 8);
            rb0 = *(const bf16x8*)(bptr + off);
            rb1 = *(const bf16x8*)(bptr + off + 8);
        }
        #pragma unroll
        for (int kk = 0; kk < 2; ++kk) {
            bf16x8 af = *(const bf16x8*)(&As[p][(w * 16 + lm) * 72 + kk * 32 + lg * 8]);
            #pragma unroll
            for (int ct = 0; ct < 4; ++ct) {
                bf16x8 bfr = *(const bf16x8*)(&Bs[p][(ct * 16 + lm) * 72 + kk * 32 + lg * 8]);
                acc[ct] = MFMA16(af, bfr, acc[ct]);
            }
        }
    }

    #pragma unroll
    for (int r = 0; r < 4; ++r) {
        float* dst = out + (size_t)(m0 + w * 16 + lg * 4 + r) * 768 + n0;
        #pragma unroll
        for (int ct = 0; ct < 4; ++ct)
            dst[ct * 16 + lm] = acc[ct][r];
    }
}

extern "C" void kernel_launch(void* const* d_in, const int* in_sizes, int n_in,
                              void* d_out, int out_size, void* d_ws, size_t ws_size,
                              hipStream_t stream) {
    const float* hs  = (const float*)d_in[0];
    const float* qw  = (const float*)d_in[1];
    const float* kw  = (const float*)d_in[2];
    const float* vw  = (const float*)d_in[3];
    const float* ow  = (const float*)d_in[4];
    const float* qln = (const float*)d_in[5];
    const float* kln = (const float*)d_in[6];
    float* out = (float*)d_out;

    float2* tab  = (float2*)d_ws;
    bf16*   q_ws = (bf16*)(tab + 65536);
    bf16*   k_ws = q_ws + 3145728;
    bf16*   vt_ws= k_ws + 1048576;
    bf16*   x_ws = vt_ws + 1048576;    // hsb during k_qkv, attn output after
    bf16*   qwb  = x_ws + 3145728;
    bf16*   kwb  = qwb + 589824;
    bf16*   vwb  = kwb + 196608;
    bf16*   owb  = vwb + 196608;

    k_prep<<<dim3(4864), 256, 0, stream>>>(hs, qw, kw, vw, ow, x_ws, qwb, kwb, vwb, owb, tab);
    k_qkv<<<dim3(64, 20, 1), 256, 0, stream>>>(x_ws, qwb, kwb, vwb, qln, kln, tab, q_ws, k_ws, vt_ws);
    k_attn<<<dim3(32, 12, 2), 128, 0, stream>>>(q_ws, k_ws, vt_ws, x_ws);
    k_oproj<<<dim3(64, 12, 1), 256, 0, stream>>>(x_ws, owb, out);
}